// Round 10
// baseline (170.652 us; speedup 1.0000x reference)
//
#include <hip/hip_runtime.h>
#include <hip/hip_bf16.h>

// B=2, T=2048, D=1024, H=16, dh=64. f32 in/out, bf16 MFMA internally.
// R10: (a) kv-permuted V^T (baked in vtrans) => P stored via cvt_pk + single
// ds_write_b128 per row (was 32 scalar u16 + 128 VALU of manual f2bf);
// (b) finer split-KV: 2-tile chunks for qt>=16 (depth<=2), 4224 blocks,
// same 33.5MB partial footprint (124 slots).

typedef __attribute__((ext_vector_type(8))) short bf16x8;
typedef __attribute__((ext_vector_type(4))) float f32x4;

__device__ __forceinline__ ushort f2bf(float f) {
  unsigned u = __builtin_bit_cast(unsigned, f);
  unsigned r = (u + 0x7fffu + ((u >> 16) & 1u)) >> 16;   // RNE
  return (ushort)r;
}
__device__ __forceinline__ float bf2f(ushort u) {
  unsigned v = ((unsigned)u) << 16;
  return __builtin_bit_cast(float, v);
}
__device__ __forceinline__ unsigned cvtpk(float a, float b) {  // [lo=a, hi=b] bf16 pair, RNE
  unsigned r;
  asm("v_cvt_pk_bf16_f32 %0, %1, %2" : "=v"(r) : "v"(a), "v"(b));
  return r;
}

__device__ __forceinline__ void gload16(const ushort* g, ushort* l) {
  auto gp = (const __attribute__((address_space(1))) void*)g;
  auto lp = (__attribute__((address_space(3))) void*)l;
  __builtin_amdgcn_global_load_lds(gp, lp, 16, 0, 0);
}

// number of KV chunks for a q-tile (must match in attn_fwd / attn_combine)
__device__ __forceinline__ int nch_of(int qt) {
  int k = (qt >> 1) + 1;
  if (k <= 2) return 1;                  // qt 0..3
  if (qt >= 16) return (k + 1) >> 1;     // 2-tile chunks
  return (k + 3) >> 2;                   // 4-tile chunks (qt 4..15; k<=8 -> nch 1..2)
}

// ---------------- convert x: f32 -> bf16 ----------------
__global__ __launch_bounds__(256) void cvt_f32_bf16(const float* __restrict__ in,
                                                    ushort* __restrict__ out, int n) {
  int i = (blockIdx.x * 256 + threadIdx.x) * 4;
  int stride = gridDim.x * 256 * 4;
  for (; i < n; i += stride) {
    float4 v = *(const float4*)(in + i);
    ushort4 o = { f2bf(v.x), f2bf(v.y), f2bf(v.z), f2bf(v.w) };
    *(ushort4*)(out + i) = o;
  }
}

// ---------------- transpose+convert: in[R][C] f32 -> out[C][R] bf16 ----------------
__global__ __launch_bounds__(256) void tcvt(const float* __restrict__ in,
                                            ushort* __restrict__ out, int R, int C) {
  __shared__ float tile[32][33];
  int c0 = blockIdx.x * 32, r0 = blockIdx.y * 32;
  int tx = threadIdx.x, ty = threadIdx.y;  // (32, 8)
  #pragma unroll
  for (int i = 0; i < 32; i += 8) tile[ty + i][tx] = in[(size_t)(r0 + ty + i) * C + c0 + tx];
  __syncthreads();
  #pragma unroll
  for (int i = 0; i < 32; i += 8) out[(size_t)(c0 + ty + i) * R + r0 + tx] = f2bf(tile[tx][ty + i]);
}

// ---------------- bf16 transpose + kv-permute: [32][2048][64] -> [32][64][2048'] --------
// out column index permuted within each 128-kv block: pos = 8*(kv&15) + ((kv>>4)&7).
// P-tile packing in attn relies on this exact permutation.
__global__ __launch_bounds__(256) void vtrans(const ushort* __restrict__ in,
                                              ushort* __restrict__ out) {
  __shared__ ushort tile[32][33];
  int t0 = blockIdx.x * 32, d0 = blockIdx.y * 32, bh = blockIdx.z;
  int tx = threadIdx.x, ty = threadIdx.y;  // (32, 8)
  const ushort* src = in + (size_t)bh * 2048 * 64;
  ushort* dst = out + (size_t)bh * 64 * 2048;
  #pragma unroll
  for (int i = 0; i < 32; i += 8) tile[ty + i][tx] = src[(size_t)(t0 + ty + i) * 64 + d0 + tx];
  __syncthreads();
  int kv = t0 + tx;
  int pp = (kv & ~127) | (((kv & 15) << 3) | ((kv >> 4) & 7));
  #pragma unroll
  for (int i = 0; i < 32; i += 8) dst[(size_t)(d0 + ty + i) * 2048 + pp] = tile[tx][ty + i];
}

// ---------------- bf16 GEMM (m97 structure): C[M,N] = A[M,K] * BT[N,K]^T ----------------
template <int EPI>
__global__ __launch_bounds__(256) void gemm_bf16(const ushort* __restrict__ A,
                                                 const ushort* __restrict__ BT,
                                                 ushort* __restrict__ qo, ushort* __restrict__ ko,
                                                 ushort* __restrict__ vo, float* __restrict__ outf,
                                                 int M, int N, int K) {
  __shared__ ushort Als[128 * 32];
  __shared__ ushort Bls[128 * 32];
  const int tid = threadIdx.x;
  const int lane = tid & 63;
  const int w = tid >> 6;
  const int wr = w >> 1, wc = w & 1;
  const int fr = lane & 15, fq = lane >> 4;
  const int bm0 = blockIdx.y * 128, bn0 = blockIdx.x * 128;
  const int srow = lane >> 2;
  const int scol = (lane & 3) * 8;

  f32x4 acc[4][4];
  #pragma unroll
  for (int m = 0; m < 4; m++)
    #pragma unroll
    for (int n = 0; n < 4; n++) acc[m][n] = (f32x4){0.f, 0.f, 0.f, 0.f};

  for (int k0 = 0; k0 < K; k0 += 32) {
    __syncthreads();
    #pragma unroll
    for (int c = 0; c < 2; c++) {
      int chunk = w * 2 + c;
      int rr = chunk * 16 + srow;
      gload16(&A[(size_t)(bm0 + rr) * K + k0 + scol], &Als[chunk * 512]);
      gload16(&BT[(size_t)(bn0 + rr) * K + k0 + scol], &Bls[chunk * 512]);
    }
    __syncthreads();
    bf16x8 a[4], b[4];
    #pragma unroll
    for (int m = 0; m < 4; m++) a[m] = *(bf16x8*)&Als[(wr * 64 + m * 16 + fr) * 32 + fq * 8];
    #pragma unroll
    for (int n = 0; n < 4; n++) b[n] = *(bf16x8*)&Bls[(wc * 64 + n * 16 + fr) * 32 + fq * 8];
    __builtin_amdgcn_s_setprio(1);
    #pragma unroll
    for (int m = 0; m < 4; m++)
      #pragma unroll
      for (int n = 0; n < 4; n++)
        acc[m][n] = __builtin_amdgcn_mfma_f32_16x16x32_bf16(a[m], b[n], acc[m][n], 0, 0, 0);
    __builtin_amdgcn_s_setprio(0);
  }

  #pragma unroll
  for (int m = 0; m < 4; m++) {
    #pragma unroll
    for (int n = 0; n < 4; n++) {
      #pragma unroll
      for (int jj = 0; jj < 4; jj++) {
        int r = bm0 + wr * 64 + m * 16 + fq * 4 + jj;
        int c = bn0 + wc * 64 + n * 16 + fr;
        float val = acc[m][n][jj];
        if (EPI == 0) {
          int which = c >> 10, h = (c >> 6) & 15, dd = c & 63;
          int b_ = r >> 11, t = r & 2047;
          size_t bh = (size_t)(b_ * 16 + h);
          ushort* dst = (which == 0) ? qo : (which == 1 ? ko : vo);
          dst[(bh * 2048 + t) * 64 + dd] = f2bf(val);
        } else {
          outf[(size_t)r * N + c] = val;
        }
      }
    }
  }
}

// ---------------- split-KV flash attention (causal), KVBLK=128 ----------
// grid 4224: bh = bx&31, i = bx>>5 (0..131, qt desc / ch asc). Partial slot = i.
// 2-tile chunks for qt>=16, 4-tile for qt in 4..15, direct (nch==1) for qt<=7.
__global__ __launch_bounds__(256, 3) void attn_fwd(const ushort* __restrict__ qg,
                                                   const ushort* __restrict__ kg,
                                                   const ushort* __restrict__ vtg,
                                                   ushort* __restrict__ y,
                                                   ushort* __restrict__ pO,
                                                   float* __restrict__ pl) {
  __shared__ ushort Ks[128 * 72];      // [kv][d]      144B rows
  __shared__ ushort Vt[64 * 136];      // [d][kv']     272B rows (kv permuted)
  __shared__ ushort Ps[4][16 * 136];   // per-wave P   [q16][kv'128] 272B rows

  const int bh = blockIdx.x & 31;
  const int i = blockIdx.x >> 5;       // 0..131
  int acc = 0, qt = 31, nch = 1;
  for (int q = 31; q >= 0; --q) {
    int nc = nch_of(q);
    if (i < acc + nc) { qt = q; nch = nc; break; }
    acc += nc;
  }
  const int ch = i - acc;
  const int k = (qt >> 1) + 1;
  const int ct = (qt >= 16) ? 2 : 4;
  const int t0 = ch * ct;
  const int t1 = (t0 + ct < k) ? t0 + ct : k;

  const int tid = threadIdx.x, lane = tid & 63, w = tid >> 6;
  const int fr = lane & 15, fq = lane >> 4;
  const size_t base = (size_t)bh * 2048 * 64;
  const int b_ = bh >> 4, h = bh & 15;
  ushort* P_ = Ps[w];

  // staging coords
  const int sr = tid >> 3;          // 0..31, K rows sr+32m
  const int sc = (tid & 7) * 8;
  const int vr = tid >> 4;          // 0..15, Vt rows vr+16m
  const int vc = (tid & 15) * 8;
  const ushort* kg_l = kg + base + (size_t)sr * 64 + sc;
  const ushort* vg_l = vtg + base + (size_t)vr * 2048 + vc;

  bf16x8 qf0 = *(const bf16x8*)&qg[base + (size_t)(qt * 64 + w * 16 + fr) * 64 + fq * 8];
  bf16x8 qf1 = *(const bf16x8*)&qg[base + (size_t)(qt * 64 + w * 16 + fr) * 64 + 32 + fq * 8];

  f32x4 o[4];
  #pragma unroll
  for (int n = 0; n < 4; n++) o[n] = (f32x4){0.f, 0.f, 0.f, 0.f};
  float l_[4] = {0.f, 0.f, 0.f, 0.f};

  uint4 k0r, k1r, k2r, k3r, v0r, v1r, v2r, v3r;  // named: cannot lower to scratch

#define LOADT(t)                                                   \
  do {                                                             \
    const ushort* kp = kg_l + (size_t)(t) * 8192;                  \
    k0r = *(const uint4*)(kp);         k1r = *(const uint4*)(kp + 2048); \
    k2r = *(const uint4*)(kp + 4096);  k3r = *(const uint4*)(kp + 6144); \
    const ushort* vp = vg_l + (size_t)(t) * 128;                   \
    v0r = *(const uint4*)(vp);              v1r = *(const uint4*)(vp + 16 * 2048); \
    v2r = *(const uint4*)(vp + 32 * 2048);  v3r = *(const uint4*)(vp + 48 * 2048); \
  } while (0)

  const float C_EXP2 = 0.18033688011112042f;  // 0.125 * log2(e)

  LOADT(t0);
  for (int t = t0; t < t1; ++t) {
    const int kv0 = t * 128;
    if (t > t0) __syncthreads();
    *(uint4*)&Ks[(size_t)sr * 72 + sc] = k0r;
    *(uint4*)&Ks[(size_t)(sr + 32) * 72 + sc] = k1r;
    *(uint4*)&Ks[(size_t)(sr + 64) * 72 + sc] = k2r;
    *(uint4*)&Ks[(size_t)(sr + 96) * 72 + sc] = k3r;
    *(uint4*)&Vt[(size_t)vr * 136 + vc] = v0r;
    *(uint4*)&Vt[(size_t)(vr + 16) * 136 + vc] = v1r;
    *(uint4*)&Vt[(size_t)(vr + 32) * 136 + vc] = v2r;
    *(uint4*)&Vt[(size_t)(vr + 48) * 136 + vc] = v3r;
    __syncthreads();

    if (t + 1 < t1) LOADT(t + 1);  // prefetch in flight across compute

    // S = Q K^T : [16 q] x [128 kv]
    f32x4 s[8];
    #pragma unroll
    for (int n = 0; n < 8; n++) s[n] = (f32x4){0.f, 0.f, 0.f, 0.f};
    __builtin_amdgcn_s_setprio(1);
    #pragma unroll
    for (int ks = 0; ks < 2; ks++) {
      bf16x8 aq = ks ? qf1 : qf0;
      #pragma unroll
      for (int n = 0; n < 8; n++) {
        bf16x8 bk = *(bf16x8*)&Ks[(n * 16 + fr) * 72 + ks * 32 + fq * 8];
        s[n] = __builtin_amdgcn_mfma_f32_16x16x32_bf16(aq, bk, s[n], 0, 0, 0);
      }
    }
    __builtin_amdgcn_s_setprio(0);

    // no-max softmax in exp2 domain; packed P row store (kv-permuted: pos = 8*fr + n)
    const bool lastT = (t == k - 1);
    #pragma unroll
    for (int j = 0; j < 4; j++) {
      const int qrow = qt * 64 + w * 16 + fq * 4 + j;
      float p[8];
      float rs = 0.f;
      #pragma unroll
      for (int n = 0; n < 8; n++) {
        float val = s[n][j] * C_EXP2;
        if (lastT && (kv0 + n * 16 + fr > qrow)) val = -1e30f;
        p[n] = __builtin_amdgcn_exp2f(val);
        rs += p[n];
      }
      l_[j] += rs;
      uint4 pk;
      pk.x = cvtpk(p[0], p[1]);
      pk.y = cvtpk(p[2], p[3]);
      pk.z = cvtpk(p[4], p[5]);
      pk.w = cvtpk(p[6], p[7]);
      *(uint4*)&P_[(fq * 4 + j) * 136 + 8 * fr] = pk;
    }

    // O += P V (both P and Vt in the same permuted kv order)
    __builtin_amdgcn_s_setprio(1);
    #pragma unroll
    for (int ks = 0; ks < 4; ks++) {
      bf16x8 pa = *(bf16x8*)&P_[fr * 136 + ks * 32 + fq * 8];
      #pragma unroll
      for (int n2 = 0; n2 < 4; n2++) {
        bf16x8 vb8 = *(bf16x8*)&Vt[(n2 * 16 + fr) * 136 + ks * 32 + fq * 8];
        o[n2] = __builtin_amdgcn_mfma_f32_16x16x32_bf16(pa, vb8, o[n2], 0, 0, 0);
      }
    }
    __builtin_amdgcn_s_setprio(0);
  }
#undef LOADT

  // cross-lane l reduction (over fr within fq group)
  #pragma unroll
  for (int j = 0; j < 4; j++) {
    float rs = l_[j];
    rs += __shfl_xor(rs, 1);
    rs += __shfl_xor(rs, 2);
    rs += __shfl_xor(rs, 4);
    rs += __shfl_xor(rs, 8);
    l_[j] = rs;
  }

  if (nch == 1) {
    #pragma unroll
    for (int n2 = 0; n2 < 4; n2++)
      #pragma unroll
      for (int j = 0; j < 4; j++) {
        int qrow = qt * 64 + w * 16 + fq * 4 + j;
        y[((size_t)(b_ * 2048 + qrow)) * 1024 + h * 64 + n2 * 16 + fr] = f2bf(o[n2][j] / l_[j]);
      }
  } else {
    const size_t ob = ((size_t)i * 32 + bh) * 64 * 64;   // slot = i (direct blocks sort last)
    #pragma unroll
    for (int n2 = 0; n2 < 4; n2++)
      #pragma unroll
      for (int j = 0; j < 4; j++) {
        int qr = w * 16 + fq * 4 + j;
        pO[ob + (size_t)qr * 64 + n2 * 16 + fr] = f2bf(o[n2][j]);
      }
    if (fr == 0) {
      #pragma unroll
      for (int j = 0; j < 4; j++)
        pl[((size_t)i * 32 + bh) * 64 + w * 16 + fq * 4 + j] = l_[j];
    }
  }
}

// ---------------- combine partials: y = (sum_c O_c) / (sum_c l_c) ----------------
__global__ __launch_bounds__(256) void attn_combine(const ushort* __restrict__ pO,
                                                    const float* __restrict__ pl,
                                                    ushort* __restrict__ y) {
  const int total = 32 * 2048 * 64;
  for (int flat = blockIdx.x * 256 + threadIdx.x; flat < total; flat += gridDim.x * 256) {
    int d = flat & 63;
    int t = (flat >> 6) & 2047;
    int bh = flat >> 17;
    int qt = t >> 6;
    int nch = nch_of(qt);
    if (nch < 2) continue;  // written directly by attn_fwd
    int baseSlot = 0;
    for (int q = 31; q > qt; --q) baseSlot += nch_of(q);
    float os = 0.f, ls = 0.f;
    for (int c = 0; c < nch; ++c) {
      int slot = baseSlot + c;
      os += bf2f(pO[((size_t)slot * 32 + bh) * 64 * 64 + (size_t)(t & 63) * 64 + d]);
      ls += pl[((size_t)slot * 32 + bh) * 64 + (t & 63)];
    }
    int b_ = bh >> 4, h = bh & 15;
    y[((size_t)(b_ * 2048 + t)) * 1024 + h * 64 + d] = f2bf(os / ls);
  }
}

extern "C" void kernel_launch(void* const* d_in, const int* in_sizes, int n_in,
                              void* d_out, int out_size, void* d_ws, size_t ws_size,
                              hipStream_t stream) {
  const float* x = (const float*)d_in[0];
  const float* wqkv = (const float*)d_in[1];
  const float* wproj = (const float*)d_in[2];
  float* out = (float*)d_out;

  ushort* ws = (ushort*)d_ws;
  ushort* xb = ws;                               // 4096*1024
  ushort* wqkvT = xb + 4096 * 1024;              // 3072*1024  [N][K]
  ushort* wprojT = wqkvT + 3072 * 1024;          // 1024*1024  [N][K]
  ushort* qb = wprojT + 1024 * 1024;             // [bh][t][64]
  ushort* kb = qb + 32 * 2048 * 64;              // [bh][t][64]
  ushort* vb = kb + 32 * 2048 * 64;              // [bh][t][64]
  ushort* vtb = vb + 32 * 2048 * 64;             // [bh][64][t'] kv-permuted
  ushort* yb = vtb + 32 * 2048 * 64;             // [B,T,1024]
  ushort* pO = yb + 4096 * 1024;                 // [128 slots][32][64][64] bf16 partial O
  float*  pl = (float*)(pO + (size_t)128 * 32 * 64 * 64);  // [128][32][64] f32

  cvt_f32_bf16<<<1024, 256, 0, stream>>>(x, xb, 4096 * 1024);
  tcvt<<<dim3(96, 32), dim3(32, 8), 0, stream>>>(wqkv, wqkvT, 1024, 3072);
  tcvt<<<dim3(32, 32), dim3(32, 8), 0, stream>>>(wproj, wprojT, 1024, 1024);

  gemm_bf16<0><<<dim3(24, 32), 256, 0, stream>>>(xb, wqkvT, qb, kb, vb, nullptr, 4096, 3072, 1024);
  vtrans<<<dim3(64, 2, 32), dim3(32, 8), 0, stream>>>(vb, vtb);
  attn_fwd<<<4224, 256, 0, stream>>>(qb, kb, vtb, yb, pO, pl);
  attn_combine<<<2048, 256, 0, stream>>>(pO, pl, yb);
  gemm_bf16<1><<<dim3(8, 32), 256, 0, stream>>>(yb, wprojT, nullptr, nullptr, nullptr, out, 4096, 1024, 1024);
}

// Round 11
// 158.904 us; speedup vs baseline: 1.0739x; 1.0739x over previous
//
#include <hip/hip_runtime.h>
#include <hip/hip_bf16.h>

// B=2, T=2048, D=1024, H=16, dh=64. f32 in/out, bf16 MFMA internally.
// R11: fix R10's vtrans regression (permuted global write was 32 scalar 2B
// stores/thread): block now owns a full 128-kv block so permuted writes are
// 16B-contiguous. gemm1 templated to BN=64 (512 blocks = 2/CU, was 1/CU).
// attn_fwd (52us, split-KV + packed P) unchanged.

typedef __attribute__((ext_vector_type(8))) short bf16x8;
typedef __attribute__((ext_vector_type(4))) float f32x4;

__device__ __forceinline__ ushort f2bf(float f) {
  unsigned u = __builtin_bit_cast(unsigned, f);
  unsigned r = (u + 0x7fffu + ((u >> 16) & 1u)) >> 16;   // RNE
  return (ushort)r;
}
__device__ __forceinline__ float bf2f(ushort u) {
  unsigned v = ((unsigned)u) << 16;
  return __builtin_bit_cast(float, v);
}
__device__ __forceinline__ unsigned cvtpk(float a, float b) {  // [lo=a, hi=b] bf16, RNE
  unsigned r;
  asm("v_cvt_pk_bf16_f32 %0, %1, %2" : "=v"(r) : "v"(a), "v"(b));
  return r;
}

__device__ __forceinline__ void gload16(const ushort* g, ushort* l) {
  auto gp = (const __attribute__((address_space(1))) void*)g;
  auto lp = (__attribute__((address_space(3))) void*)l;
  __builtin_amdgcn_global_load_lds(gp, lp, 16, 0, 0);
}

// number of KV chunks for a q-tile (must match attn_fwd / attn_combine)
__device__ __forceinline__ int nch_of(int qt) {
  int k = (qt >> 1) + 1;
  if (k <= 2) return 1;
  if (qt >= 16) return (k + 1) >> 1;
  return (k + 3) >> 2;
}

// ---------------- convert x: f32 -> bf16 ----------------
__global__ __launch_bounds__(256) void cvt_f32_bf16(const float* __restrict__ in,
                                                    ushort* __restrict__ out, int n) {
  int i = (blockIdx.x * 256 + threadIdx.x) * 4;
  int stride = gridDim.x * 256 * 4;
  for (; i < n; i += stride) {
    float4 v = *(const float4*)(in + i);
    ushort4 o = { f2bf(v.x), f2bf(v.y), f2bf(v.z), f2bf(v.w) };
    *(ushort4*)(out + i) = o;
  }
}

// ---------------- transpose+convert: in[R][C] f32 -> out[C][R] bf16 ----------------
__global__ __launch_bounds__(256) void tcvt(const float* __restrict__ in,
                                            ushort* __restrict__ out, int R, int C) {
  __shared__ float tile[32][33];
  int c0 = blockIdx.x * 32, r0 = blockIdx.y * 32;
  int tx = threadIdx.x, ty = threadIdx.y;  // (32, 8)
  #pragma unroll
  for (int i = 0; i < 32; i += 8) tile[ty + i][tx] = in[(size_t)(r0 + ty + i) * C + c0 + tx];
  __syncthreads();
  #pragma unroll
  for (int i = 0; i < 32; i += 8) out[(size_t)(c0 + ty + i) * R + r0 + tx] = f2bf(tile[tx][ty + i]);
}

// ---------------- bf16 transpose + kv-permute, fully vectorized ----------------
// [32][2048][64] -> [32][64][2048'], pos within 128-block = 8*(kv&15) + (kv>>4)&7.
// Block owns 128 kv x 32 d => permuted writes are 16B-contiguous uint4.
__global__ __launch_bounds__(256) void vtrans(const ushort* __restrict__ in,
                                              ushort* __restrict__ out) {
  __shared__ ushort tile[128][40];  // [kv][d], stride 40 keeps 16B alignment
  const int t0 = blockIdx.x * 128, d0 = blockIdx.y * 32, bh = blockIdx.z;
  const int tid = threadIdx.x;
  const ushort* src = in + (size_t)bh * 2048 * 64;
  ushort* dst = out + (size_t)bh * 64 * 2048;
  #pragma unroll
  for (int p = 0; p < 2; p++) {
    int idx = tid + p * 256;            // 0..511
    int r = idx >> 2, c8 = (idx & 3) * 8;
    *(uint4*)&tile[r][c8] = *(const uint4*)&src[(size_t)(t0 + r) * 64 + d0 + c8];
  }
  __syncthreads();
  #pragma unroll
  for (int p = 0; p < 2; p++) {
    int idx = tid + p * 256;
    int d = idx >> 4;                   // 0..31
    int m = idx & 15;                   // output positions 8m..8m+7  (= kv 16e+m)
    ushort vals[8];
    #pragma unroll
    for (int e = 0; e < 8; e++) vals[e] = tile[16 * e + m][d];
    *(uint4*)&dst[(size_t)(d0 + d) * 2048 + t0 + 8 * m] = *(uint4*)vals;
  }
}

// ---------------- bf16 GEMM (m97 structure): C[M,N] = A[M,K] * BT[N,K]^T ----------------
// BM=128 fixed; BN templated (128 or 64). 4 waves as 2x2; wave = 64 x BN/2.
template <int EPI, int BN>
__global__ __launch_bounds__(256) void gemm_bf16(const ushort* __restrict__ A,
                                                 const ushort* __restrict__ BT,
                                                 ushort* __restrict__ qo, ushort* __restrict__ ko,
                                                 ushort* __restrict__ vo, float* __restrict__ outf,
                                                 int M, int N, int K) {
  constexpr int NB = BN / 32;          // col frags per wave
  __shared__ ushort Als[128 * 32];
  __shared__ ushort Bls[BN * 32];
  const int tid = threadIdx.x;
  const int lane = tid & 63;
  const int w = tid >> 6;
  const int wr = w >> 1, wc = w & 1;
  const int fr = lane & 15, fq = lane >> 4;
  const int bm0 = blockIdx.y * 128, bn0 = blockIdx.x * BN;
  const int srow = lane >> 2;
  const int scol = (lane & 3) * 8;

  f32x4 acc[4][NB];
  #pragma unroll
  for (int m = 0; m < 4; m++)
    #pragma unroll
    for (int n = 0; n < NB; n++) acc[m][n] = (f32x4){0.f, 0.f, 0.f, 0.f};

  for (int k0 = 0; k0 < K; k0 += 32) {
    __syncthreads();
    #pragma unroll
    for (int c = 0; c < 2; c++) {
      int chunk = w * 2 + c;
      int rr = chunk * 16 + srow;
      gload16(&A[(size_t)(bm0 + rr) * K + k0 + scol], &Als[chunk * 512]);
    }
    #pragma unroll
    for (int c = 0; c < BN / 64; c++) {
      int chunk = w * (BN / 64) + c;
      int rr = chunk * 16 + srow;
      gload16(&BT[(size_t)(bn0 + rr) * K + k0 + scol], &Bls[chunk * 512]);
    }
    __syncthreads();
    bf16x8 a[4], b[NB];
    #pragma unroll
    for (int m = 0; m < 4; m++) a[m] = *(bf16x8*)&Als[(wr * 64 + m * 16 + fr) * 32 + fq * 8];
    #pragma unroll
    for (int n = 0; n < NB; n++) b[n] = *(bf16x8*)&Bls[(wc * (BN / 2) + n * 16 + fr) * 32 + fq * 8];
    __builtin_amdgcn_s_setprio(1);
    #pragma unroll
    for (int m = 0; m < 4; m++)
      #pragma unroll
      for (int n = 0; n < NB; n++)
        acc[m][n] = __builtin_amdgcn_mfma_f32_16x16x32_bf16(a[m], b[n], acc[m][n], 0, 0, 0);
    __builtin_amdgcn_s_setprio(0);
  }

  #pragma unroll
  for (int m = 0; m < 4; m++) {
    #pragma unroll
    for (int n = 0; n < NB; n++) {
      #pragma unroll
      for (int jj = 0; jj < 4; jj++) {
        int r = bm0 + wr * 64 + m * 16 + fq * 4 + jj;
        int c = bn0 + wc * (BN / 2) + n * 16 + fr;
        float val = acc[m][n][jj];
        if (EPI == 0) {
          int which = c >> 10, h = (c >> 6) & 15, dd = c & 63;
          int b_ = r >> 11, t = r & 2047;
          size_t bh = (size_t)(b_ * 16 + h);
          ushort* dst = (which == 0) ? qo : (which == 1 ? ko : vo);
          dst[(bh * 2048 + t) * 64 + dd] = f2bf(val);
        } else {
          outf[(size_t)r * N + c] = val;
        }
      }
    }
  }
}

// ---------------- split-KV flash attention (causal), KVBLK=128 ----------
// grid 4224: bh = bx&31, i = bx>>5 (qt desc / ch asc). Slot = i.
__global__ __launch_bounds__(256, 3) void attn_fwd(const ushort* __restrict__ qg,
                                                   const ushort* __restrict__ kg,
                                                   const ushort* __restrict__ vtg,
                                                   ushort* __restrict__ y,
                                                   ushort* __restrict__ pO,
                                                   float* __restrict__ pl) {
  __shared__ ushort Ks[128 * 72];      // [kv][d]
  __shared__ ushort Vt[64 * 136];      // [d][kv'] (kv permuted)
  __shared__ ushort Ps[4][16 * 136];   // per-wave P [q16][kv'128]

  const int bh = blockIdx.x & 31;
  const int i = blockIdx.x >> 5;
  int acc = 0, qt = 31, nch = 1;
  for (int q = 31; q >= 0; --q) {
    int nc = nch_of(q);
    if (i < acc + nc) { qt = q; nch = nc; break; }
    acc += nc;
  }
  const int ch = i - acc;
  const int k = (qt >> 1) + 1;
  const int ct = (qt >= 16) ? 2 : 4;
  const int t0 = ch * ct;
  const int t1 = (t0 + ct < k) ? t0 + ct : k;

  const int tid = threadIdx.x, lane = tid & 63, w = tid >> 6;
  const int fr = lane & 15, fq = lane >> 4;
  const size_t base = (size_t)bh * 2048 * 64;
  const int b_ = bh >> 4, h = bh & 15;
  ushort* P_ = Ps[w];

  const int sr = tid >> 3;          // 0..31
  const int sc = (tid & 7) * 8;
  const int vr = tid >> 4;          // 0..15
  const int vc = (tid & 15) * 8;
  const ushort* kg_l = kg + base + (size_t)sr * 64 + sc;
  const ushort* vg_l = vtg + base + (size_t)vr * 2048 + vc;

  bf16x8 qf0 = *(const bf16x8*)&qg[base + (size_t)(qt * 64 + w * 16 + fr) * 64 + fq * 8];
  bf16x8 qf1 = *(const bf16x8*)&qg[base + (size_t)(qt * 64 + w * 16 + fr) * 64 + 32 + fq * 8];

  f32x4 o[4];
  #pragma unroll
  for (int n = 0; n < 4; n++) o[n] = (f32x4){0.f, 0.f, 0.f, 0.f};
  float l_[4] = {0.f, 0.f, 0.f, 0.f};

  uint4 k0r, k1r, k2r, k3r, v0r, v1r, v2r, v3r;  // named: cannot lower to scratch

#define LOADT(t)                                                   \
  do {                                                             \
    const ushort* kp = kg_l + (size_t)(t) * 8192;                  \
    k0r = *(const uint4*)(kp);         k1r = *(const uint4*)(kp + 2048); \
    k2r = *(const uint4*)(kp + 4096);  k3r = *(const uint4*)(kp + 6144); \
    const ushort* vp = vg_l + (size_t)(t) * 128;                   \
    v0r = *(const uint4*)(vp);              v1r = *(const uint4*)(vp + 16 * 2048); \
    v2r = *(const uint4*)(vp + 32 * 2048);  v3r = *(const uint4*)(vp + 48 * 2048); \
  } while (0)

  const float C_EXP2 = 0.18033688011112042f;  // 0.125 * log2(e)

  LOADT(t0);
  for (int t = t0; t < t1; ++t) {
    const int kv0 = t * 128;
    if (t > t0) __syncthreads();
    *(uint4*)&Ks[(size_t)sr * 72 + sc] = k0r;
    *(uint4*)&Ks[(size_t)(sr + 32) * 72 + sc] = k1r;
    *(uint4*)&Ks[(size_t)(sr + 64) * 72 + sc] = k2r;
    *(uint4*)&Ks[(size_t)(sr + 96) * 72 + sc] = k3r;
    *(uint4*)&Vt[(size_t)vr * 136 + vc] = v0r;
    *(uint4*)&Vt[(size_t)(vr + 16) * 136 + vc] = v1r;
    *(uint4*)&Vt[(size_t)(vr + 32) * 136 + vc] = v2r;
    *(uint4*)&Vt[(size_t)(vr + 48) * 136 + vc] = v3r;
    __syncthreads();

    if (t + 1 < t1) LOADT(t + 1);  // prefetch in flight across compute

    // S = Q K^T
    f32x4 s[8];
    #pragma unroll
    for (int n = 0; n < 8; n++) s[n] = (f32x4){0.f, 0.f, 0.f, 0.f};
    __builtin_amdgcn_s_setprio(1);
    #pragma unroll
    for (int ks = 0; ks < 2; ks++) {
      bf16x8 aq = ks ? qf1 : qf0;
      #pragma unroll
      for (int n = 0; n < 8; n++) {
        bf16x8 bk = *(bf16x8*)&Ks[(n * 16 + fr) * 72 + ks * 32 + fq * 8];
        s[n] = __builtin_amdgcn_mfma_f32_16x16x32_bf16(aq, bk, s[n], 0, 0, 0);
      }
    }
    __builtin_amdgcn_s_setprio(0);

    // no-max softmax; packed P row store (kv-permuted: pos = 8*fr + n)
    const bool lastT = (t == k - 1);
    #pragma unroll
    for (int j = 0; j < 4; j++) {
      const int qrow = qt * 64 + w * 16 + fq * 4 + j;
      float p[8];
      float rs = 0.f;
      #pragma unroll
      for (int n = 0; n < 8; n++) {
        float val = s[n][j] * C_EXP2;
        if (lastT && (kv0 + n * 16 + fr > qrow)) val = -1e30f;
        p[n] = __builtin_amdgcn_exp2f(val);
        rs += p[n];
      }
      l_[j] += rs;
      uint4 pk;
      pk.x = cvtpk(p[0], p[1]);
      pk.y = cvtpk(p[2], p[3]);
      pk.z = cvtpk(p[4], p[5]);
      pk.w = cvtpk(p[6], p[7]);
      *(uint4*)&P_[(fq * 4 + j) * 136 + 8 * fr] = pk;
    }

    // O += P V (P and Vt share the permuted kv order)
    __builtin_amdgcn_s_setprio(1);
    #pragma unroll
    for (int ks = 0; ks < 4; ks++) {
      bf16x8 pa = *(bf16x8*)&P_[fr * 136 + ks * 32 + fq * 8];
      #pragma unroll
      for (int n2 = 0; n2 < 4; n2++) {
        bf16x8 vb8 = *(bf16x8*)&Vt[(n2 * 16 + fr) * 136 + ks * 32 + fq * 8];
        o[n2] = __builtin_amdgcn_mfma_f32_16x16x32_bf16(pa, vb8, o[n2], 0, 0, 0);
      }
    }
    __builtin_amdgcn_s_setprio(0);
  }
#undef LOADT

  #pragma unroll
  for (int j = 0; j < 4; j++) {
    float rs = l_[j];
    rs += __shfl_xor(rs, 1);
    rs += __shfl_xor(rs, 2);
    rs += __shfl_xor(rs, 4);
    rs += __shfl_xor(rs, 8);
    l_[j] = rs;
  }

  if (nch == 1) {
    #pragma unroll
    for (int n2 = 0; n2 < 4; n2++)
      #pragma unroll
      for (int j = 0; j < 4; j++) {
        int qrow = qt * 64 + w * 16 + fq * 4 + j;
        y[((size_t)(b_ * 2048 + qrow)) * 1024 + h * 64 + n2 * 16 + fr] = f2bf(o[n2][j] / l_[j]);
      }
  } else {
    const size_t ob = ((size_t)i * 32 + bh) * 64 * 64;
    #pragma unroll
    for (int n2 = 0; n2 < 4; n2++)
      #pragma unroll
      for (int j = 0; j < 4; j++) {
        int qr = w * 16 + fq * 4 + j;
        pO[ob + (size_t)qr * 64 + n2 * 16 + fr] = f2bf(o[n2][j]);
      }
    if (fr == 0) {
      #pragma unroll
      for (int j = 0; j < 4; j++)
        pl[((size_t)i * 32 + bh) * 64 + w * 16 + fq * 4 + j] = l_[j];
    }
  }
}

// ---------------- combine partials: y = (sum_c O_c) / (sum_c l_c) ----------------
__global__ __launch_bounds__(256) void attn_combine(const ushort* __restrict__ pO,
                                                    const float* __restrict__ pl,
                                                    ushort* __restrict__ y) {
  const int total = 32 * 2048 * 64;
  for (int flat = blockIdx.x * 256 + threadIdx.x; flat < total; flat += gridDim.x * 256) {
    int d = flat & 63;
    int t = (flat >> 6) & 2047;
    int bh = flat >> 17;
    int qt = t >> 6;
    int nch = nch_of(qt);
    if (nch < 2) continue;
    int baseSlot = 0;
    for (int q = 31; q > qt; --q) baseSlot += nch_of(q);
    float os = 0.f, ls = 0.f;
    for (int c = 0; c < nch; ++c) {
      int slot = baseSlot + c;
      os += bf2f(pO[((size_t)slot * 32 + bh) * 64 * 64 + (size_t)(t & 63) * 64 + d]);
      ls += pl[((size_t)slot * 32 + bh) * 64 + (t & 63)];
    }
    int b_ = bh >> 4, h = bh & 15;
    y[((size_t)(b_ * 2048 + t)) * 1024 + h * 64 + d] = f2bf(os / ls);
  }
}

extern "C" void kernel_launch(void* const* d_in, const int* in_sizes, int n_in,
                              void* d_out, int out_size, void* d_ws, size_t ws_size,
                              hipStream_t stream) {
  const float* x = (const float*)d_in[0];
  const float* wqkv = (const float*)d_in[1];
  const float* wproj = (const float*)d_in[2];
  float* out = (float*)d_out;

  ushort* ws = (ushort*)d_ws;
  ushort* xb = ws;                               // 4096*1024
  ushort* wqkvT = xb + 4096 * 1024;              // 3072*1024  [N][K]
  ushort* wprojT = wqkvT + 3072 * 1024;          // 1024*1024  [N][K]
  ushort* qb = wprojT + 1024 * 1024;             // [bh][t][64]
  ushort* kb = qb + 32 * 2048 * 64;              // [bh][t][64]
  ushort* vb = kb + 32 * 2048 * 64;              // [bh][t][64]
  ushort* vtb = vb + 32 * 2048 * 64;             // [bh][64][t'] kv-permuted
  ushort* yb = vtb + 32 * 2048 * 64;             // [B,T,1024]
  ushort* pO = yb + 4096 * 1024;                 // [132 slots][32][64][64] bf16
  float*  pl = (float*)(pO + (size_t)132 * 32 * 64 * 64);  // [132][32][64] f32

  cvt_f32_bf16<<<1024, 256, 0, stream>>>(x, xb, 4096 * 1024);
  tcvt<<<dim3(96, 32), dim3(32, 8), 0, stream>>>(wqkv, wqkvT, 1024, 3072);
  tcvt<<<dim3(32, 32), dim3(32, 8), 0, stream>>>(wproj, wprojT, 1024, 1024);

  gemm_bf16<0, 128><<<dim3(24, 32), 256, 0, stream>>>(xb, wqkvT, qb, kb, vb, nullptr, 4096, 3072, 1024);
  vtrans<<<dim3(16, 2, 32), 256, 0, stream>>>(vb, vtb);
  attn_fwd<<<4224, 256, 0, stream>>>(qb, kb, vtb, yb, pO, pl);
  attn_combine<<<2048, 256, 0, stream>>>(pO, pl, yb);
  gemm_bf16<1, 64><<<dim3(16, 32), 256, 0, stream>>>(yb, wprojT, nullptr, nullptr, nullptr, out, 4096, 1024, 1024);
}

// Round 13
// 150.126 us; speedup vs baseline: 1.1367x; 1.0585x over previous
//
#include <hip/hip_runtime.h>
#include <hip/hip_bf16.h>

// B=2, T=2048, D=1024, H=16, dh=64. f32 in/out, bf16 MFMA internally.
// R13 = R12 with prep-cvt coverage fix (R12 converted only 1/4 of x: dropped
// grid-stride loop). 5 launches: prep, gemm0 (fused V-transpose epilogue),
// attn (52us), combine, gemm1 (BN=64).

typedef __attribute__((ext_vector_type(8))) short bf16x8;
typedef __attribute__((ext_vector_type(4))) float f32x4;

__device__ __forceinline__ ushort f2bf(float f) {
  unsigned u = __builtin_bit_cast(unsigned, f);
  unsigned r = (u + 0x7fffu + ((u >> 16) & 1u)) >> 16;   // RNE
  return (ushort)r;
}
__device__ __forceinline__ float bf2f(ushort u) {
  unsigned v = ((unsigned)u) << 16;
  return __builtin_bit_cast(float, v);
}
__device__ __forceinline__ unsigned cvtpk(float a, float b) {  // [lo=a, hi=b] bf16, RNE
  unsigned r;
  asm("v_cvt_pk_bf16_f32 %0, %1, %2" : "=v"(r) : "v"(a), "v"(b));
  return r;
}

__device__ __forceinline__ void gload16(const ushort* g, ushort* l) {
  auto gp = (const __attribute__((address_space(1))) void*)g;
  auto lp = (__attribute__((address_space(3))) void*)l;
  __builtin_amdgcn_global_load_lds(gp, lp, 16, 0, 0);
}

// number of KV chunks for a q-tile (must match attn_fwd / attn_combine)
__device__ __forceinline__ int nch_of(int qt) {
  int k = (qt >> 1) + 1;
  if (k <= 2) return 1;
  if (qt >= 16) return (k + 1) >> 1;
  return (k + 3) >> 2;
}

// ---------------- prep: x cvt + w_qkv^T + w_proj^T in ONE launch ----------------
// blocks [0,4096): cvt x (full coverage, 1 pass);
// [4096,7168): tcvt wqkv; [7168,8192): tcvt wproj
__global__ __launch_bounds__(256) void prep(const float* __restrict__ x,
                                            const float* __restrict__ wq,
                                            const float* __restrict__ wp,
                                            ushort* __restrict__ xb,
                                            ushort* __restrict__ wqT,
                                            ushort* __restrict__ wpT) {
  __shared__ float tile[32][33];
  const int bx = blockIdx.x;
  if (bx < 4096) {
    int i = (bx * 256 + threadIdx.x) * 4;     // 4096*256*4 = 4,194,304 = |x|
    float4 v = *(const float4*)(x + i);
    ushort4 o = { f2bf(v.x), f2bf(v.y), f2bf(v.z), f2bf(v.w) };
    *(ushort4*)(xb + i) = o;
    return;
  }
  const float* in;  ushort* out;  int C, b2;
  if (bx < 7168) { b2 = bx - 4096; in = wq; out = wqT; C = 3072; }
  else           { b2 = bx - 7168; in = wp; out = wpT; C = 1024; }
  const int R = 1024;
  int nbx = C / 32;
  int c0 = (b2 % nbx) * 32, r0 = (b2 / nbx) * 32;
  int tx = threadIdx.x & 31, ty = threadIdx.x >> 5;
  #pragma unroll
  for (int i = 0; i < 32; i += 8) tile[ty + i][tx] = in[(size_t)(r0 + ty + i) * C + c0 + tx];
  __syncthreads();
  #pragma unroll
  for (int i = 0; i < 32; i += 8) out[(size_t)(c0 + ty + i) * R + r0 + tx] = f2bf(tile[tx][ty + i]);
}

// ---------------- bf16 GEMM (m97 structure): C[M,N] = A[M,K] * BT[N,K]^T ----------------
// EPI=0 (BN=128): LDS-staged coalesced epilogue; bn0<2048 -> q/k rows,
// bn0>=2048 -> V written TRANSPOSED + kv-permuted straight to vtb (vo).
// EPI=1: f32 store to outf.
template <int EPI, int BN>
__global__ __launch_bounds__(256) void gemm_bf16(const ushort* __restrict__ A,
                                                 const ushort* __restrict__ BT,
                                                 ushort* __restrict__ qo, ushort* __restrict__ ko,
                                                 ushort* __restrict__ vo, float* __restrict__ outf,
                                                 int M, int N, int K) {
  constexpr int NB = BN / 32;
  constexpr int ABU = 128 * 32 + BN * 32;                  // ushorts for Als+Bls
  constexpr int SHU = (EPI == 0 && 2 * 128 * 72 > ABU) ? 2 * 128 * 72 : ABU;
  __shared__ ushort sh[SHU];
  ushort* Als = sh;
  ushort* Bls = sh + 128 * 32;
  const int tid = threadIdx.x;
  const int lane = tid & 63;
  const int w = tid >> 6;
  const int wr = w >> 1, wc = w & 1;
  const int fr = lane & 15, fq = lane >> 4;
  const int bm0 = blockIdx.y * 128, bn0 = blockIdx.x * BN;
  const int srow = lane >> 2;
  const int scol = (lane & 3) * 8;

  f32x4 acc[4][NB];
  #pragma unroll
  for (int m = 0; m < 4; m++)
    #pragma unroll
    for (int n = 0; n < NB; n++) acc[m][n] = (f32x4){0.f, 0.f, 0.f, 0.f};

  for (int k0 = 0; k0 < K; k0 += 32) {
    __syncthreads();
    #pragma unroll
    for (int c = 0; c < 2; c++) {
      int chunk = w * 2 + c;
      int rr = chunk * 16 + srow;
      gload16(&A[(size_t)(bm0 + rr) * K + k0 + scol], &Als[chunk * 512]);
    }
    #pragma unroll
    for (int c = 0; c < BN / 64; c++) {
      int chunk = w * (BN / 64) + c;
      int rr = chunk * 16 + srow;
      gload16(&BT[(size_t)(bn0 + rr) * K + k0 + scol], &Bls[chunk * 512]);
    }
    __syncthreads();
    bf16x8 a[4], b[NB];
    #pragma unroll
    for (int m = 0; m < 4; m++) a[m] = *(bf16x8*)&Als[(wr * 64 + m * 16 + fr) * 32 + fq * 8];
    #pragma unroll
    for (int n = 0; n < NB; n++) b[n] = *(bf16x8*)&Bls[(wc * (BN / 2) + n * 16 + fr) * 32 + fq * 8];
    __builtin_amdgcn_s_setprio(1);
    #pragma unroll
    for (int m = 0; m < 4; m++)
      #pragma unroll
      for (int n = 0; n < NB; n++)
        acc[m][n] = __builtin_amdgcn_mfma_f32_16x16x32_bf16(a[m], b[n], acc[m][n], 0, 0, 0);
    __builtin_amdgcn_s_setprio(0);
  }

  if (EPI == 0) {
    // stage bf16 outputs to LDS [2 heads][128 t][72], then coalesced writeback
    __syncthreads();                       // all waves done with Als/Bls
    ushort* vst = sh;
    #pragma unroll
    for (int m = 0; m < 4; m++)
      #pragma unroll
      for (int n = 0; n < NB; n++)
        #pragma unroll
        for (int jj = 0; jj < 4; jj++) {
          int lt = wr * 64 + m * 16 + fq * 4 + jj;   // local t 0..127
          int dd = n * 16 + fr;                      // 0..63 within head wc
          vst[(wc * 128 + lt) * 72 + dd] = f2bf(acc[m][n][jj]);
        }
    __syncthreads();
    const int b_ = bm0 >> 11, t0loc = bm0 & 2047;
    const int which = bn0 >> 10;
    const int hbase = (bn0 & 1023) >> 6;
    if (which < 2) {                        // q or k: straight row copy
      ushort* dst = (which == 0) ? qo : ko;
      #pragma unroll
      for (int p = 0; p < 8; p++) {
        int idx = tid + p * 256;            // 0..2047
        int hh = idx >> 10, lt = (idx >> 3) & 127, c8 = (idx & 7) * 8;
        uint4 v = *(uint4*)&vst[(hh * 128 + lt) * 72 + c8];
        size_t bh = (size_t)(b_ * 16 + hbase + hh);
        *(uint4*)&dst[(bh * 2048 + t0loc + lt) * 64 + c8] = v;
      }
    } else {                                // V: transpose + kv-permute (pos = 8m + e)
      #pragma unroll
      for (int p = 0; p < 8; p++) {
        int idx = tid + p * 256;
        int hh = idx >> 10, d = (idx >> 4) & 63, m = idx & 15;
        ushort vals[8];
        #pragma unroll
        for (int e = 0; e < 8; e++) vals[e] = vst[(hh * 128 + 16 * e + m) * 72 + d];
        size_t bh = (size_t)(b_ * 16 + hbase + hh);
        *(uint4*)&vo[(bh * 64 + d) * 2048 + t0loc + 8 * m] = *(uint4*)vals;
      }
    }
  } else {
    #pragma unroll
    for (int m = 0; m < 4; m++)
      #pragma unroll
      for (int n = 0; n < NB; n++)
        #pragma unroll
        for (int jj = 0; jj < 4; jj++) {
          int r = bm0 + wr * 64 + m * 16 + fq * 4 + jj;
          int c = bn0 + wc * (BN / 2) + n * 16 + fr;
          outf[(size_t)r * N + c] = acc[m][n][jj];
        }
  }
}

// ---------------- split-KV flash attention (causal), KVBLK=128 ----------
// grid 4224: bh = bx&31, i = bx>>5 (qt desc / ch asc). Slot = i.
__global__ __launch_bounds__(256, 3) void attn_fwd(const ushort* __restrict__ qg,
                                                   const ushort* __restrict__ kg,
                                                   const ushort* __restrict__ vtg,
                                                   ushort* __restrict__ y,
                                                   ushort* __restrict__ pO,
                                                   float* __restrict__ pl) {
  __shared__ ushort Ks[128 * 72];      // [kv][d]
  __shared__ ushort Vt[64 * 136];      // [d][kv'] (kv permuted)
  __shared__ ushort Ps[4][16 * 136];   // per-wave P [q16][kv'128]

  const int bh = blockIdx.x & 31;
  const int i = blockIdx.x >> 5;
  int acc = 0, qt = 31, nch = 1;
  for (int q = 31; q >= 0; --q) {
    int nc = nch_of(q);
    if (i < acc + nc) { qt = q; nch = nc; break; }
    acc += nc;
  }
  const int ch = i - acc;
  const int k = (qt >> 1) + 1;
  const int ct = (qt >= 16) ? 2 : 4;
  const int t0 = ch * ct;
  const int t1 = (t0 + ct < k) ? t0 + ct : k;

  const int tid = threadIdx.x, lane = tid & 63, w = tid >> 6;
  const int fr = lane & 15, fq = lane >> 4;
  const size_t base = (size_t)bh * 2048 * 64;
  const int b_ = bh >> 4, h = bh & 15;
  ushort* P_ = Ps[w];

  const int sr = tid >> 3;          // 0..31
  const int sc = (tid & 7) * 8;
  const int vr = tid >> 4;          // 0..15
  const int vc = (tid & 15) * 8;
  const ushort* kg_l = kg + base + (size_t)sr * 64 + sc;
  const ushort* vg_l = vtg + base + (size_t)vr * 2048 + vc;

  bf16x8 qf0 = *(const bf16x8*)&qg[base + (size_t)(qt * 64 + w * 16 + fr) * 64 + fq * 8];
  bf16x8 qf1 = *(const bf16x8*)&qg[base + (size_t)(qt * 64 + w * 16 + fr) * 64 + 32 + fq * 8];

  f32x4 o[4];
  #pragma unroll
  for (int n = 0; n < 4; n++) o[n] = (f32x4){0.f, 0.f, 0.f, 0.f};
  float l_[4] = {0.f, 0.f, 0.f, 0.f};

  uint4 k0r, k1r, k2r, k3r, v0r, v1r, v2r, v3r;  // named: cannot lower to scratch

#define LOADT(t)                                                   \
  do {                                                             \
    const ushort* kp = kg_l + (size_t)(t) * 8192;                  \
    k0r = *(const uint4*)(kp);         k1r = *(const uint4*)(kp + 2048); \
    k2r = *(const uint4*)(kp + 4096);  k3r = *(const uint4*)(kp + 6144); \
    const ushort* vp = vg_l + (size_t)(t) * 128;                   \
    v0r = *(const uint4*)(vp);              v1r = *(const uint4*)(vp + 16 * 2048); \
    v2r = *(const uint4*)(vp + 32 * 2048);  v3r = *(const uint4*)(vp + 48 * 2048); \
  } while (0)

  const float C_EXP2 = 0.18033688011112042f;  // 0.125 * log2(e)

  LOADT(t0);
  for (int t = t0; t < t1; ++t) {
    const int kv0 = t * 128;
    if (t > t0) __syncthreads();
    *(uint4*)&Ks[(size_t)sr * 72 + sc] = k0r;
    *(uint4*)&Ks[(size_t)(sr + 32) * 72 + sc] = k1r;
    *(uint4*)&Ks[(size_t)(sr + 64) * 72 + sc] = k2r;
    *(uint4*)&Ks[(size_t)(sr + 96) * 72 + sc] = k3r;
    *(uint4*)&Vt[(size_t)vr * 136 + vc] = v0r;
    *(uint4*)&Vt[(size_t)(vr + 16) * 136 + vc] = v1r;
    *(uint4*)&Vt[(size_t)(vr + 32) * 136 + vc] = v2r;
    *(uint4*)&Vt[(size_t)(vr + 48) * 136 + vc] = v3r;
    __syncthreads();

    if (t + 1 < t1) LOADT(t + 1);  // prefetch in flight across compute

    // S = Q K^T
    f32x4 s[8];
    #pragma unroll
    for (int n = 0; n < 8; n++) s[n] = (f32x4){0.f, 0.f, 0.f, 0.f};
    __builtin_amdgcn_s_setprio(1);
    #pragma unroll
    for (int ks = 0; ks < 2; ks++) {
      bf16x8 aq = ks ? qf1 : qf0;
      #pragma unroll
      for (int n = 0; n < 8; n++) {
        bf16x8 bk = *(bf16x8*)&Ks[(n * 16 + fr) * 72 + ks * 32 + fq * 8];
        s[n] = __builtin_amdgcn_mfma_f32_16x16x32_bf16(aq, bk, s[n], 0, 0, 0);
      }
    }
    __builtin_amdgcn_s_setprio(0);

    // no-max softmax; packed P row store (kv-permuted: pos = 8*fr + n)
    const bool lastT = (t == k - 1);
    #pragma unroll
    for (int j = 0; j < 4; j++) {
      const int qrow = qt * 64 + w * 16 + fq * 4 + j;
      float p[8];
      float rs = 0.f;
      #pragma unroll
      for (int n = 0; n < 8; n++) {
        float val = s[n][j] * C_EXP2;
        if (lastT && (kv0 + n * 16 + fr > qrow)) val = -1e30f;
        p[n] = __builtin_amdgcn_exp2f(val);
        rs += p[n];
      }
      l_[j] += rs;
      uint4 pk;
      pk.x = cvtpk(p[0], p[1]);
      pk.y = cvtpk(p[2], p[3]);
      pk.z = cvtpk(p[4], p[5]);
      pk.w = cvtpk(p[6], p[7]);
      *(uint4*)&P_[(fq * 4 + j) * 136 + 8 * fr] = pk;
    }

    // O += P V (P and Vt share the permuted kv order)
    __builtin_amdgcn_s_setprio(1);
    #pragma unroll
    for (int ks = 0; ks < 4; ks++) {
      bf16x8 pa = *(bf16x8*)&P_[fr * 136 + ks * 32 + fq * 8];
      #pragma unroll
      for (int n2 = 0; n2 < 4; n2++) {
        bf16x8 vb8 = *(bf16x8*)&Vt[(n2 * 16 + fr) * 136 + ks * 32 + fq * 8];
        o[n2] = __builtin_amdgcn_mfma_f32_16x16x32_bf16(pa, vb8, o[n2], 0, 0, 0);
      }
    }
    __builtin_amdgcn_s_setprio(0);
  }
#undef LOADT

  #pragma unroll
  for (int j = 0; j < 4; j++) {
    float rs = l_[j];
    rs += __shfl_xor(rs, 1);
    rs += __shfl_xor(rs, 2);
    rs += __shfl_xor(rs, 4);
    rs += __shfl_xor(rs, 8);
    l_[j] = rs;
  }

  if (nch == 1) {
    #pragma unroll
    for (int n2 = 0; n2 < 4; n2++)
      #pragma unroll
      for (int j = 0; j < 4; j++) {
        int qrow = qt * 64 + w * 16 + fq * 4 + j;
        y[((size_t)(b_ * 2048 + qrow)) * 1024 + h * 64 + n2 * 16 + fr] = f2bf(o[n2][j] / l_[j]);
      }
  } else {
    const size_t ob = ((size_t)i * 32 + bh) * 64 * 64;
    #pragma unroll
    for (int n2 = 0; n2 < 4; n2++)
      #pragma unroll
      for (int j = 0; j < 4; j++) {
        int qr = w * 16 + fq * 4 + j;
        pO[ob + (size_t)qr * 64 + n2 * 16 + fr] = f2bf(o[n2][j]);
      }
    if (fr == 0) {
      #pragma unroll
      for (int j = 0; j < 4; j++)
        pl[((size_t)i * 32 + bh) * 64 + w * 16 + fq * 4 + j] = l_[j];
    }
  }
}

// ---------------- combine partials: y = (sum_c O_c) / (sum_c l_c) ----------------
__global__ __launch_bounds__(256) void attn_combine(const ushort* __restrict__ pO,
                                                    const float* __restrict__ pl,
                                                    ushort* __restrict__ y) {
  const int total = 32 * 2048 * 64;
  for (int flat = blockIdx.x * 256 + threadIdx.x; flat < total; flat += gridDim.x * 256) {
    int d = flat & 63;
    int t = (flat >> 6) & 2047;
    int bh = flat >> 17;
    int qt = t >> 6;
    int nch = nch_of(qt);
    if (nch < 2) continue;
    int baseSlot = 0;
    for (int q = 31; q > qt; --q) baseSlot += nch_of(q);
    float os = 0.f, ls = 0.f;
    for (int c = 0; c < nch; ++c) {
      int slot = baseSlot + c;
      os += bf2f(pO[((size_t)slot * 32 + bh) * 64 * 64 + (size_t)(t & 63) * 64 + d]);
      ls += pl[((size_t)slot * 32 + bh) * 64 + (t & 63)];
    }
    int b_ = bh >> 4, h = bh & 15;
    y[((size_t)(b_ * 2048 + t)) * 1024 + h * 64 + d] = f2bf(os / ls);
  }
}

extern "C" void kernel_launch(void* const* d_in, const int* in_sizes, int n_in,
                              void* d_out, int out_size, void* d_ws, size_t ws_size,
                              hipStream_t stream) {
  const float* x = (const float*)d_in[0];
  const float* wqkv = (const float*)d_in[1];
  const float* wproj = (const float*)d_in[2];
  float* out = (float*)d_out;

  ushort* ws = (ushort*)d_ws;
  ushort* xb = ws;                               // 4096*1024
  ushort* wqkvT = xb + 4096 * 1024;              // 3072*1024  [N][K]
  ushort* wprojT = wqkvT + 3072 * 1024;          // 1024*1024  [N][K]
  ushort* qb = wprojT + 1024 * 1024;             // [bh][t][64]
  ushort* kb = qb + 32 * 2048 * 64;              // [bh][t][64]
  ushort* vtb = kb + 32 * 2048 * 64;             // [bh][64][t'] kv-permuted (direct from gemm0)
  ushort* yb = vtb + 32 * 2048 * 64;             // [B,T,1024]
  ushort* pO = yb + 4096 * 1024;                 // [132 slots][32][64][64] bf16
  float*  pl = (float*)(pO + (size_t)132 * 32 * 64 * 64);  // [132][32][64] f32

  prep<<<8192, 256, 0, stream>>>(x, wqkv, wproj, xb, wqkvT, wprojT);
  gemm_bf16<0, 128><<<dim3(24, 32), 256, 0, stream>>>(xb, wqkvT, qb, kb, vtb, nullptr, 4096, 3072, 1024);
  attn_fwd<<<4224, 256, 0, stream>>>(qb, kb, vtb, yb, pO, pl);
  attn_combine<<<2048, 256, 0, stream>>>(pO, pl, yb);
  gemm_bf16<1, 64><<<dim3(16, 32), 256, 0, stream>>>(yb, wprojT, nullptr, nullptr, nullptr, out, 4096, 1024, 1024);
}

// Round 14
// 137.428 us; speedup vs baseline: 1.2418x; 1.0924x over previous
//
#include <hip/hip_runtime.h>
#include <hip/hip_bf16.h>

// B=2, T=2048, D=1024, H=16, dh=64. f32 in/out, bf16 MFMA internally.
// R14: attn q32 (wave owns 32 q-rows; K/V LDS frag reads reused across 2 MFMA
// row-groups: -42% LDS ops/FLOP, the measured bottleneck) + XCD-chunked block
// swizzle on both GEMMs. 5 launches.

typedef __attribute__((ext_vector_type(8))) short bf16x8;
typedef __attribute__((ext_vector_type(4))) float f32x4;

__device__ __forceinline__ ushort f2bf(float f) {
  unsigned u = __builtin_bit_cast(unsigned, f);
  unsigned r = (u + 0x7fffu + ((u >> 16) & 1u)) >> 16;   // RNE
  return (ushort)r;
}
__device__ __forceinline__ float bf2f(ushort u) {
  unsigned v = ((unsigned)u) << 16;
  return __builtin_bit_cast(float, v);
}
__device__ __forceinline__ unsigned cvtpk(float a, float b) {  // [lo=a, hi=b] bf16, RNE
  unsigned r;
  asm("v_cvt_pk_bf16_f32 %0, %1, %2" : "=v"(r) : "v"(a), "v"(b));
  return r;
}

__device__ __forceinline__ void gload16(const ushort* g, ushort* l) {
  auto gp = (const __attribute__((address_space(1))) void*)g;
  auto lp = (__attribute__((address_space(3))) void*)l;
  __builtin_amdgcn_global_load_lds(gp, lp, 16, 0, 0);
}

// chunks per 128-row q-block a (k = a+1 kv tiles); must match attn/combine
__device__ __forceinline__ int nch2_of(int a) {
  if (a >= 8) return (a + 2) >> 1;   // 2-tile chunks: ceil((a+1)/2)
  if (a >= 4) return 2;              // 4-tile chunks, k=5..8
  return 1;                          // k<=4, single chunk
}

// ---------------- prep: x cvt + w_qkv^T + w_proj^T in ONE launch ----------------
__global__ __launch_bounds__(256) void prep(const float* __restrict__ x,
                                            const float* __restrict__ wq,
                                            const float* __restrict__ wp,
                                            ushort* __restrict__ xb,
                                            ushort* __restrict__ wqT,
                                            ushort* __restrict__ wpT) {
  __shared__ float tile[32][33];
  const int bx = blockIdx.x;
  if (bx < 4096) {
    int i = (bx * 256 + threadIdx.x) * 4;     // 4096*256*4 = |x|
    float4 v = *(const float4*)(x + i);
    ushort4 o = { f2bf(v.x), f2bf(v.y), f2bf(v.z), f2bf(v.w) };
    *(ushort4*)(xb + i) = o;
    return;
  }
  const float* in;  ushort* out;  int C, b2;
  if (bx < 7168) { b2 = bx - 4096; in = wq; out = wqT; C = 3072; }
  else           { b2 = bx - 7168; in = wp; out = wpT; C = 1024; }
  const int R = 1024;
  int nbx = C / 32;
  int c0 = (b2 % nbx) * 32, r0 = (b2 / nbx) * 32;
  int tx = threadIdx.x & 31, ty = threadIdx.x >> 5;
  #pragma unroll
  for (int i = 0; i < 32; i += 8) tile[ty + i][tx] = in[(size_t)(r0 + ty + i) * C + c0 + tx];
  __syncthreads();
  #pragma unroll
  for (int i = 0; i < 32; i += 8) out[(size_t)(c0 + ty + i) * R + r0 + tx] = f2bf(tile[tx][ty + i]);
}

// ---------------- bf16 GEMM: C[M,N] = A[M,K] * BT[N,K]^T, XCD-chunked 1D grid --------
// M=4096 (32 tiles of 128) fixed. EPI=0 (BN=128): fused q/k/v epilogue
// (v transposed + kv-permuted). EPI=1: f32 store.
template <int EPI, int BN>
__global__ __launch_bounds__(256) void gemm_bf16(const ushort* __restrict__ A,
                                                 const ushort* __restrict__ BT,
                                                 ushort* __restrict__ qo, ushort* __restrict__ ko,
                                                 ushort* __restrict__ vo, float* __restrict__ outf,
                                                 int M, int N, int K) {
  constexpr int NB = BN / 32;
  constexpr int ABU = 128 * 32 + BN * 32;
  constexpr int SHU = (EPI == 0 && 2 * 128 * 72 > ABU) ? 2 * 128 * 72 : ABU;
  __shared__ ushort sh[SHU];
  ushort* Als = sh;
  ushort* Bls = sh + 128 * 32;
  const int tid = threadIdx.x;
  const int lane = tid & 63;
  const int w = tid >> 6;
  const int wr = w >> 1, wc = w & 1;
  const int fr = lane & 15, fq = lane >> 4;
  // XCD-chunked swizzle (grid = 32 * N/BN, divisible by 8): each XCD gets a
  // contiguous M-fast chunk -> shares B-panels in its private L2.
  const int flat = blockIdx.x;
  const int cpx = (32 * (N / BN)) >> 3;
  const int swz = (flat & 7) * cpx + (flat >> 3);
  const int bm0 = (swz & 31) * 128;
  const int bn0 = (swz >> 5) * BN;
  const int srow = lane >> 2;
  const int scol = (lane & 3) * 8;

  f32x4 acc[4][NB];
  #pragma unroll
  for (int m = 0; m < 4; m++)
    #pragma unroll
    for (int n = 0; n < NB; n++) acc[m][n] = (f32x4){0.f, 0.f, 0.f, 0.f};

  for (int k0 = 0; k0 < K; k0 += 32) {
    __syncthreads();
    #pragma unroll
    for (int c = 0; c < 2; c++) {
      int chunk = w * 2 + c;
      int rr = chunk * 16 + srow;
      gload16(&A[(size_t)(bm0 + rr) * K + k0 + scol], &Als[chunk * 512]);
    }
    #pragma unroll
    for (int c = 0; c < BN / 64; c++) {
      int chunk = w * (BN / 64) + c;
      int rr = chunk * 16 + srow;
      gload16(&BT[(size_t)(bn0 + rr) * K + k0 + scol], &Bls[chunk * 512]);
    }
    __syncthreads();
    bf16x8 a[4], b[NB];
    #pragma unroll
    for (int m = 0; m < 4; m++) a[m] = *(bf16x8*)&Als[(wr * 64 + m * 16 + fr) * 32 + fq * 8];
    #pragma unroll
    for (int n = 0; n < NB; n++) b[n] = *(bf16x8*)&Bls[(wc * (BN / 2) + n * 16 + fr) * 32 + fq * 8];
    __builtin_amdgcn_s_setprio(1);
    #pragma unroll
    for (int m = 0; m < 4; m++)
      #pragma unroll
      for (int n = 0; n < NB; n++)
        acc[m][n] = __builtin_amdgcn_mfma_f32_16x16x32_bf16(a[m], b[n], acc[m][n], 0, 0, 0);
    __builtin_amdgcn_s_setprio(0);
  }

  if (EPI == 0) {
    __syncthreads();
    ushort* vst = sh;
    #pragma unroll
    for (int m = 0; m < 4; m++)
      #pragma unroll
      for (int n = 0; n < NB; n++)
        #pragma unroll
        for (int jj = 0; jj < 4; jj++) {
          int lt = wr * 64 + m * 16 + fq * 4 + jj;
          int dd = n * 16 + fr;
          vst[(wc * 128 + lt) * 72 + dd] = f2bf(acc[m][n][jj]);
        }
    __syncthreads();
    const int b_ = bm0 >> 11, t0loc = bm0 & 2047;
    const int which = bn0 >> 10;
    const int hbase = (bn0 & 1023) >> 6;
    if (which < 2) {
      ushort* dst = (which == 0) ? qo : ko;
      #pragma unroll
      for (int p = 0; p < 8; p++) {
        int idx = tid + p * 256;
        int hh = idx >> 10, lt = (idx >> 3) & 127, c8 = (idx & 7) * 8;
        uint4 v = *(uint4*)&vst[(hh * 128 + lt) * 72 + c8];
        size_t bh = (size_t)(b_ * 16 + hbase + hh);
        *(uint4*)&dst[(bh * 2048 + t0loc + lt) * 64 + c8] = v;
      }
    } else {
      #pragma unroll
      for (int p = 0; p < 8; p++) {
        int idx = tid + p * 256;
        int hh = idx >> 10, d = (idx >> 4) & 63, m = idx & 15;
        ushort vals[8];
        #pragma unroll
        for (int e = 0; e < 8; e++) vals[e] = vst[(hh * 128 + 16 * e + m) * 72 + d];
        size_t bh = (size_t)(b_ * 16 + hbase + hh);
        *(uint4*)&vo[(bh * 64 + d) * 2048 + t0loc + 8 * m] = *(uint4*)vals;
      }
    }
  } else {
    #pragma unroll
    for (int m = 0; m < 4; m++)
      #pragma unroll
      for (int n = 0; n < NB; n++)
        #pragma unroll
        for (int jj = 0; jj < 4; jj++) {
          int r = bm0 + wr * 64 + m * 16 + fq * 4 + jj;
          int c = bn0 + wc * (BN / 2) + n * 16 + fr;
          outf[(size_t)r * N + c] = acc[m][n][jj];
        }
  }
}

// ---------------- split-KV flash attention (causal), q32 waves, KVBLK=128 ----------
// Block = 128 q-rows (q-block a = rows [128a,128a+128); tiles 2a,2a+1 share k=a+1).
// 4 waves; wave w owns 32 q-rows as two 16-row MFMA groups -> K/V frag reads
// feed 2 MFMAs each. grid 2048: bh=bx&31, i=bx>>5 in [0,64).
__global__ __launch_bounds__(256, 2) void attn_fwd(const ushort* __restrict__ qg,
                                                   const ushort* __restrict__ kg,
                                                   const ushort* __restrict__ vtg,
                                                   ushort* __restrict__ y,
                                                   ushort* __restrict__ pO,
                                                   float* __restrict__ pl) {
  __shared__ ushort Ks[128 * 72];      // [kv][d]
  __shared__ ushort Vt[64 * 136];      // [d][kv'] (kv permuted)
  __shared__ ushort Ps[4][32 * 136];   // per-wave P [q32][kv'128]

  const int bh = blockIdx.x & 31;
  const int i = blockIdx.x >> 5;       // 0..63, a descending
  int acc = 0, a = 15, nch = 1;
  for (int q = 15; q >= 0; --q) {
    int nc = nch2_of(q);
    if (i < acc + nc) { a = q; nch = nc; break; }
    acc += nc;
  }
  const int ch = i - acc;
  const int k = a + 1;
  const int ct = (a >= 8) ? 2 : 4;
  const int t0 = ch * ct;
  const int t1 = (t0 + ct < k) ? t0 + ct : k;

  const int tid = threadIdx.x, lane = tid & 63, w = tid >> 6;
  const int fr = lane & 15, fq = lane >> 4;
  const size_t base = (size_t)bh * 2048 * 64;
  const int b_ = bh >> 4, h = bh & 15;
  const int qb0 = a * 128;
  ushort* P_ = Ps[w];

  const int sr = tid >> 3;          // 0..31
  const int sc = (tid & 7) * 8;
  const int vr = tid >> 4;          // 0..15
  const int vc = (tid & 15) * 8;
  const ushort* kg_l = kg + base + (size_t)sr * 64 + sc;
  const ushort* vg_l = vtg + base + (size_t)vr * 2048 + vc;

  bf16x8 qf[2][2];
  #pragma unroll
  for (int g = 0; g < 2; g++) {
    const ushort* qp = &qg[base + (size_t)(qb0 + w * 32 + g * 16 + fr) * 64];
    qf[g][0] = *(const bf16x8*)(qp + fq * 8);
    qf[g][1] = *(const bf16x8*)(qp + 32 + fq * 8);
  }

  f32x4 o[2][4];
  #pragma unroll
  for (int g = 0; g < 2; g++)
    #pragma unroll
    for (int n = 0; n < 4; n++) o[g][n] = (f32x4){0.f, 0.f, 0.f, 0.f};
  float l_[2][4] = {{0.f,0.f,0.f,0.f},{0.f,0.f,0.f,0.f}};

  uint4 k0r, k1r, k2r, k3r, v0r, v1r, v2r, v3r;  // named: cannot lower to scratch

#define LOADT(t)                                                   \
  do {                                                             \
    const ushort* kp = kg_l + (size_t)(t) * 8192;                  \
    k0r = *(const uint4*)(kp);         k1r = *(const uint4*)(kp + 2048); \
    k2r = *(const uint4*)(kp + 4096);  k3r = *(const uint4*)(kp + 6144); \
    const ushort* vp = vg_l + (size_t)(t) * 128;                   \
    v0r = *(const uint4*)(vp);              v1r = *(const uint4*)(vp + 16 * 2048); \
    v2r = *(const uint4*)(vp + 32 * 2048);  v3r = *(const uint4*)(vp + 48 * 2048); \
  } while (0)

  const float C_EXP2 = 0.18033688011112042f;  // 0.125 * log2(e)

  LOADT(t0);
  for (int t = t0; t < t1; ++t) {
    const int kv0 = t * 128;
    if (t > t0) __syncthreads();
    *(uint4*)&Ks[(size_t)sr * 72 + sc] = k0r;
    *(uint4*)&Ks[(size_t)(sr + 32) * 72 + sc] = k1r;
    *(uint4*)&Ks[(size_t)(sr + 64) * 72 + sc] = k2r;
    *(uint4*)&Ks[(size_t)(sr + 96) * 72 + sc] = k3r;
    *(uint4*)&Vt[(size_t)vr * 136 + vc] = v0r;
    *(uint4*)&Vt[(size_t)(vr + 16) * 136 + vc] = v1r;
    *(uint4*)&Vt[(size_t)(vr + 32) * 136 + vc] = v2r;
    *(uint4*)&Vt[(size_t)(vr + 48) * 136 + vc] = v3r;
    __syncthreads();

    if (t + 1 < t1) LOADT(t + 1);  // prefetch in flight across compute

    // S = Q K^T : [32 q] x [128 kv]; each K frag read feeds 2 MFMAs
    f32x4 s[2][8];
    #pragma unroll
    for (int g = 0; g < 2; g++)
      #pragma unroll
      for (int n = 0; n < 8; n++) s[g][n] = (f32x4){0.f, 0.f, 0.f, 0.f};
    __builtin_amdgcn_s_setprio(1);
    #pragma unroll
    for (int ks = 0; ks < 2; ks++)
      #pragma unroll
      for (int n = 0; n < 8; n++) {
        bf16x8 bk = *(bf16x8*)&Ks[(n * 16 + fr) * 72 + ks * 32 + fq * 8];
        s[0][n] = __builtin_amdgcn_mfma_f32_16x16x32_bf16(qf[0][ks], bk, s[0][n], 0, 0, 0);
        s[1][n] = __builtin_amdgcn_mfma_f32_16x16x32_bf16(qf[1][ks], bk, s[1][n], 0, 0, 0);
      }
    __builtin_amdgcn_s_setprio(0);

    // no-max softmax; packed P row store (kv-permuted: pos = 8*fr + n)
    const bool lastT = (t == k - 1);
    #pragma unroll
    for (int g = 0; g < 2; g++)
      #pragma unroll
      for (int j = 0; j < 4; j++) {
        const int qrow = qb0 + w * 32 + g * 16 + fq * 4 + j;
        float p[8];
        float rs = 0.f;
        #pragma unroll
        for (int n = 0; n < 8; n++) {
          float val = s[g][n][j] * C_EXP2;
          if (lastT && (kv0 + n * 16 + fr > qrow)) val = -1e30f;
          p[n] = __builtin_amdgcn_exp2f(val);
          rs += p[n];
        }
        l_[g][j] += rs;
        uint4 pk;
        pk.x = cvtpk(p[0], p[1]);
        pk.y = cvtpk(p[2], p[3]);
        pk.z = cvtpk(p[4], p[5]);
        pk.w = cvtpk(p[6], p[7]);
        *(uint4*)&P_[(g * 16 + fq * 4 + j) * 136 + 8 * fr] = pk;
      }

    // O += P V; each V frag read feeds 2 MFMAs
    __builtin_amdgcn_s_setprio(1);
    #pragma unroll
    for (int ks = 0; ks < 4; ks++) {
      bf16x8 pa0 = *(bf16x8*)&P_[fr * 136 + ks * 32 + fq * 8];
      bf16x8 pa1 = *(bf16x8*)&P_[(16 + fr) * 136 + ks * 32 + fq * 8];
      #pragma unroll
      for (int n2 = 0; n2 < 4; n2++) {
        bf16x8 vb8 = *(bf16x8*)&Vt[(n2 * 16 + fr) * 136 + ks * 32 + fq * 8];
        o[0][n2] = __builtin_amdgcn_mfma_f32_16x16x32_bf16(pa0, vb8, o[0][n2], 0, 0, 0);
        o[1][n2] = __builtin_amdgcn_mfma_f32_16x16x32_bf16(pa1, vb8, o[1][n2], 0, 0, 0);
      }
    }
    __builtin_amdgcn_s_setprio(0);
  }
#undef LOADT

  #pragma unroll
  for (int g = 0; g < 2; g++)
    #pragma unroll
    for (int j = 0; j < 4; j++) {
      float rs = l_[g][j];
      rs += __shfl_xor(rs, 1);
      rs += __shfl_xor(rs, 2);
      rs += __shfl_xor(rs, 4);
      rs += __shfl_xor(rs, 8);
      l_[g][j] = rs;
    }

  if (nch == 1) {
    #pragma unroll
    for (int g = 0; g < 2; g++)
      #pragma unroll
      for (int n2 = 0; n2 < 4; n2++)
        #pragma unroll
        for (int j = 0; j < 4; j++) {
          int qrow = qb0 + w * 32 + g * 16 + fq * 4 + j;
          y[((size_t)(b_ * 2048 + qrow)) * 1024 + h * 64 + n2 * 16 + fr] =
              f2bf(o[g][n2][j] / l_[g][j]);
        }
  } else {
    const size_t ob = ((size_t)i * 32 + bh) * 128 * 64;
    #pragma unroll
    for (int g = 0; g < 2; g++)
      #pragma unroll
      for (int n2 = 0; n2 < 4; n2++)
        #pragma unroll
        for (int j = 0; j < 4; j++) {
          int qr = w * 32 + g * 16 + fq * 4 + j;
          pO[ob + (size_t)qr * 64 + n2 * 16 + fr] = f2bf(o[g][n2][j]);
        }
    if (fr == 0) {
      #pragma unroll
      for (int g = 0; g < 2; g++)
        #pragma unroll
        for (int j = 0; j < 4; j++)
          pl[((size_t)i * 32 + bh) * 128 + w * 32 + g * 16 + fq * 4 + j] = l_[g][j];
    }
  }
}

// ---------------- combine partials: y = (sum_c O_c) / (sum_c l_c) ----------------
__global__ __launch_bounds__(256) void attn_combine(const ushort* __restrict__ pO,
                                                    const float* __restrict__ pl,
                                                    ushort* __restrict__ y) {
  const int total = 32 * 2048 * 64;
  for (int flat = blockIdx.x * 256 + threadIdx.x; flat < total; flat += gridDim.x * 256) {
    int d = flat & 63;
    int t = (flat >> 6) & 2047;
    int bh = flat >> 17;
    int a = t >> 7;
    int nch = nch2_of(a);
    if (nch < 2) continue;
    int baseSlot = 0;
    for (int q = 15; q > a; --q) baseSlot += nch2_of(q);
    float os = 0.f, ls = 0.f;
    for (int c = 0; c < nch; ++c) {
      int slot = baseSlot + c;
      os += bf2f(pO[((size_t)slot * 32 + bh) * 128 * 64 + (size_t)(t & 127) * 64 + d]);
      ls += pl[((size_t)slot * 32 + bh) * 128 + (t & 127)];
    }
    int b_ = bh >> 4, h = bh & 15;
    y[((size_t)(b_ * 2048 + t)) * 1024 + h * 64 + d] = f2bf(os / ls);
  }
}

extern "C" void kernel_launch(void* const* d_in, const int* in_sizes, int n_in,
                              void* d_out, int out_size, void* d_ws, size_t ws_size,
                              hipStream_t stream) {
  const float* x = (const float*)d_in[0];
  const float* wqkv = (const float*)d_in[1];
  const float* wproj = (const float*)d_in[2];
  float* out = (float*)d_out;

  ushort* ws = (ushort*)d_ws;
  ushort* xb = ws;                               // 4096*1024
  ushort* wqkvT = xb + 4096 * 1024;              // 3072*1024  [N][K]
  ushort* wprojT = wqkvT + 3072 * 1024;          // 1024*1024  [N][K]
  ushort* qb = wprojT + 1024 * 1024;             // [bh][t][64]
  ushort* kb = qb + 32 * 2048 * 64;              // [bh][t][64]
  ushort* vtb = kb + 32 * 2048 * 64;             // [bh][64][t'] kv-permuted
  ushort* yb = vtb + 32 * 2048 * 64;             // [B,T,1024]
  ushort* pO = yb + 4096 * 1024;                 // [64 slots][32][128][64] bf16
  float*  pl = (float*)(pO + (size_t)64 * 32 * 128 * 64);  // [64][32][128] f32

  prep<<<8192, 256, 0, stream>>>(x, wqkv, wproj, xb, wqkvT, wprojT);
  gemm_bf16<0, 128><<<768, 256, 0, stream>>>(xb, wqkvT, qb, kb, vtb, nullptr, 4096, 3072, 1024);
  attn_fwd<<<2048, 256, 0, stream>>>(qb, kb, vtb, yb, pO, pl);
  attn_combine<<<2048, 256, 0, stream>>>(pO, pl, yb);
  gemm_bf16<1, 64><<<512, 256, 0, stream>>>(yb, wprojT, nullptr, nullptr, nullptr, out, 4096, 1024, 1024);
}